// Round 14
// baseline (1980.064 us; speedup 1.0000x reference)
//
#include <hip/hip_runtime.h>
#include <hip/hip_fp16.h>

#define HID 6
#define NUM_GRAPHS 1000
#define BSH 11
#define BN (1 << BSH)           // 2048 nodes per bucket (src AND dst)
#define MAXNB 512
#define CHUNK 3072
#define PERT  12                // CHUNK / 256
#define LTB 1024

__device__ __forceinline__ unsigned pk2(float a, float b) {
    __half2 h = __floats2half2_rn(a, b);
    return *(unsigned*)&h;
}
__device__ __forceinline__ float2 up2(unsigned u) {
    __half2 h = *(__half2*)&u;
    return __half22float2(h);
}
__device__ __forceinline__ uint4 ldnt16(const uint4* p) {
    const unsigned long long* q = (const unsigned long long*)p;
    unsigned long long lo = __builtin_nontemporal_load(q);
    unsigned long long hi = __builtin_nontemporal_load(q + 1);
    uint4 r;
    r.x = (unsigned)lo; r.y = (unsigned)(lo >> 32);
    r.z = (unsigned)hi; r.w = (unsigned)(hi >> 32);
    return r;
}

// ===========================================================================
__global__ void pad_kernel(const float* __restrict__ x, uint4* __restrict__ h16, int N) {
    int i = blockIdx.x * blockDim.x + threadIdx.x;
    if (i >= N) return;
    const float2* s = (const float2*)(x + (size_t)i * HID);
    float2 a = s[0], b = s[1], c = s[2];
    uint4 o;
    o.x = pk2(a.x, a.y); o.y = pk2(b.x, b.y); o.z = pk2(c.x, c.y); o.w = 0;
    h16[i] = o;
}

__global__ void init_cursor_kernel(int* __restrict__ cur, int NB, int cap) {
    int b = blockIdx.x * blockDim.x + threadIdx.x;
    if (b < NB) cur[b] = b * cap;
}

// ===========================================================================
// prep (once): bin edges by src-bucket. record {ea fp16 x6, dst<<11 | srcLow11}
// ===========================================================================
__global__ void __launch_bounds__(256) prep_kernel(
        const int* __restrict__ src, const int* __restrict__ dst,
        const float* __restrict__ ea,
        int* __restrict__ gcursorS,
        uint4* __restrict__ srcbin,
        int E, int capS, int NBs) {
    __shared__ uint4 pay[CHUNK];                     // 48 KB
    __shared__ unsigned short sb_[CHUNK];            // 6 KB
    __shared__ int hist[MAXNB], cnt[MAXNB], base[MAXNB], lofs[MAXNB], pairs[256];

    int t = threadIdx.x;
    long e0 = (long)blockIdx.x * CHUNK;
    long rem = (long)E - e0;
    int count = (int)(rem < CHUNK ? rem : CHUNK);

    for (int b = t; b < MAXNB; b += 256) { hist[b] = 0; cnt[b] = 0; }
    __syncthreads();

    int s_[PERT], d_[PERT];
#pragma unroll
    for (int j = 0; j < PERT; ++j) {
        int le = t + j * 256;
        if (le < count) {
            s_[j] = src[e0 + le];
            d_[j] = dst[e0 + le];
            atomicAdd(&hist[s_[j] >> BSH], 1);
        } else { s_[j] = -1; }
    }
    __syncthreads();

    {   // scan hist[0..512) -> lofs
        int b0 = 2 * t, b1 = 2 * t + 1;
        int s0 = hist[b0], s1 = hist[b1];
        pairs[t] = s0 + s1;
        __syncthreads();
        for (int off = 1; off < 256; off <<= 1) {
            int a = (t >= off) ? pairs[t - off] : 0;
            __syncthreads();
            pairs[t] += a;
            __syncthreads();
        }
        int excl = (t == 0) ? 0 : pairs[t - 1];
        lofs[b0] = excl;
        lofs[b1] = excl + s0;
    }
    for (int b = t; b < NBs; b += 256) {
        int c = hist[b];
        base[b] = c ? atomicAdd(&gcursorS[b], c) : 0;
    }
    __syncthreads();

#pragma unroll
    for (int j = 0; j < PERT; ++j) {
        if (s_[j] < 0) continue;
        int b = s_[j] >> BSH;
        long e = e0 + (t + j * 256);
        const float2* ep = (const float2*)(ea + (size_t)e * HID);
        float2 A = ep[0], B = ep[1], C = ep[2];
        uint4 p;
        p.x = pk2(A.x, A.y);
        p.y = pk2(B.x, B.y);
        p.z = pk2(C.x, C.y);
        p.w = ((unsigned)d_[j] << BSH) | (unsigned)(s_[j] & (BN - 1));
        int r = atomicAdd(&cnt[b], 1);
        int slot = lofs[b] + r;
        pay[slot] = p;
        sb_[slot] = (unsigned short)b;
    }
    __syncthreads();

    for (int s2 = t; s2 < count; s2 += 256) {
        int b = sb_[s2];
        long gpos = (long)base[b] + (s2 - lofs[b]);
        srcbin[gpos] = pay[s2];
    }
}

// ===========================================================================
// layer A: per src-bucket chunk, compute m = relu(h[src]+ea) (h from 32KB
// L1-resident window) and LDS-bin m-records by dst bucket. Coalesced IO only.
// out record: {m fp16 x6, dloc11}
// ===========================================================================
__global__ void __launch_bounds__(256) layerA_kernel(
        const uint4* __restrict__ h16,
        const uint4* __restrict__ srcbin,
        const int* __restrict__ gcursorS,
        int* __restrict__ gcursorD,
        uint4* __restrict__ mbin,
        int capS, int chpr, int NBd) {
    __shared__ uint4 pay[CHUNK];                     // 48 KB
    __shared__ unsigned short sb_[CHUNK];            // 6 KB
    __shared__ int hist[MAXNB], cnt2[MAXNB], base[MAXNB], lofs[MAXNB], pairs[256];

    int t = threadIdx.x;
    int sreg = blockIdx.x / chpr;
    int ci   = blockIdx.x % chpr;
    int regCnt = gcursorS[sreg] - sreg * capS;
    int count = regCnt - ci * CHUNK;
    if (count <= 0) return;                          // uniform per block
    if (count > CHUNK) count = CHUNK;
    long m0 = (long)sreg * capS + (long)ci * CHUNK;
    int sbase = sreg << BSH;

    for (int b = t; b < MAXNB; b += 256) { hist[b] = 0; cnt2[b] = 0; }
    __syncthreads();

    uint4 r_[PERT];
    int bk_[PERT];
#pragma unroll
    for (int j = 0; j < PERT; ++j) {
        int le = t + j * 256;
        if (le < count) {
            uint4 rec = ldnt16(srcbin + m0 + le);
            int s = sbase | (rec.w & (BN - 1));
            unsigned dd = rec.w >> BSH;
            uint4 hv = h16[s];                        // 32KB window -> L1
            float2 e01 = up2(rec.x), e23 = up2(rec.y), e45 = up2(rec.z);
            float2 h01 = up2(hv.x),  h23 = up2(hv.y),  h45 = up2(hv.z);
            uint4 o;
            o.x = pk2(fmaxf(h01.x + e01.x, 0.f), fmaxf(h01.y + e01.y, 0.f));
            o.y = pk2(fmaxf(h23.x + e23.x, 0.f), fmaxf(h23.y + e23.y, 0.f));
            o.z = pk2(fmaxf(h45.x + e45.x, 0.f), fmaxf(h45.y + e45.y, 0.f));
            o.w = dd & (BN - 1);                      // dloc
            r_[j] = o;
            bk_[j] = dd >> BSH;
            atomicAdd(&hist[bk_[j]], 1);
        } else bk_[j] = -1;
    }
    __syncthreads();

    {   // scan hist[0..512) -> lofs
        int b0 = 2 * t, b1 = 2 * t + 1;
        int s0 = hist[b0], s1 = hist[b1];
        pairs[t] = s0 + s1;
        __syncthreads();
        for (int off = 1; off < 256; off <<= 1) {
            int a = (t >= off) ? pairs[t - off] : 0;
            __syncthreads();
            pairs[t] += a;
            __syncthreads();
        }
        int excl = (t == 0) ? 0 : pairs[t - 1];
        lofs[b0] = excl;
        lofs[b1] = excl + s0;
    }
    for (int b = t; b < NBd; b += 256) {
        int c = hist[b];
        base[b] = c ? atomicAdd(&gcursorD[b], c) : 0;
    }
    __syncthreads();

#pragma unroll
    for (int j = 0; j < PERT; ++j) {
        if (bk_[j] < 0) continue;
        int b = bk_[j];
        int r = atomicAdd(&cnt2[b], 1);
        int slot = lofs[b] + r;
        pay[slot] = r_[j];
        sb_[slot] = (unsigned short)b;
    }
    __syncthreads();

    for (int s2 = t; s2 < count; s2 += 256) {
        int b = sb_[s2];
        long gpos = (long)base[b] + (s2 - lofs[b]);
        mbin[gpos] = pay[s2];
    }
}

// ===========================================================================
// layer B: one block per dst bucket; stream m-records, LDS accumulate,
// node update epilogue. Coalesced IO only.
// ===========================================================================
#define M_UPD(P)                                                              \
    do {                                                                      \
        int dl_ = P.w & (BN - 1);                                             \
        float2 m01 = up2(P.x), m23 = up2(P.y), m45 = up2(P.z);                \
        float* pp = sagg + (size_t)dl_ * HID;                                 \
        atomicAdd(pp + 0, m01.x); atomicAdd(pp + 1, m01.y);                   \
        atomicAdd(pp + 2, m23.x); atomicAdd(pp + 3, m23.y);                   \
        atomicAdd(pp + 4, m45.x); atomicAdd(pp + 5, m45.y);                   \
    } while (0)

__device__ __forceinline__ void accum_m(float* sagg, const uint4* __restrict__ mbin,
                                        long kbeg, int cnt, int t) {
    int k4 = cnt & ~(4 * LTB - 1);
    for (int k = t; k < k4; k += 4 * LTB) {
        uint4 p0 = ldnt16(mbin + kbeg + k);
        uint4 p1 = ldnt16(mbin + kbeg + k + LTB);
        uint4 p2 = ldnt16(mbin + kbeg + k + 2 * LTB);
        uint4 p3 = ldnt16(mbin + kbeg + k + 3 * LTB);
        M_UPD(p0); M_UPD(p1); M_UPD(p2); M_UPD(p3);
    }
    for (int k = k4 + t; k < cnt; k += LTB) {
        uint4 p = ldnt16(mbin + kbeg + k);
        M_UPD(p);
    }
}

__global__ void __launch_bounds__(LTB) layerB_kernel(
        const uint4* __restrict__ h16,
        const uint4* __restrict__ mbin,
        const int* __restrict__ gcursorD,
        const float* __restrict__ W, const float* __restrict__ b,
        uint4* __restrict__ out16, int N, int capD) {
    __shared__ float sagg[BN * HID];     // 48 KB
    __shared__ float sW[HID * HID];
    __shared__ float sb[HID];
    int t = threadIdx.x;
    int bk = blockIdx.x;
    if (t < HID * HID) sW[t] = W[t];
    if (t < HID) sb[t] = b[t];
    for (int i = t; i < BN * HID; i += LTB) sagg[i] = 0.f;
    __syncthreads();

    long kbeg = (long)bk * capD;
    int cnt = gcursorD[bk] - (int)kbeg;
    accum_m(sagg, mbin, kbeg, cnt, t);
    __syncthreads();

    int nodeBase = bk << BSH;
    for (int n = t; n < BN; n += LTB) {
        int i = nodeBase + n;
        if (i >= N) break;
        uint4 hv = h16[i];
        float2 h01 = up2(hv.x), h23 = up2(hv.y), h45 = up2(hv.z);
        const float* sp = sagg + (size_t)n * HID;
        float tv[HID];
        tv[0] = h01.x + sp[0]; tv[1] = h01.y + sp[1]; tv[2] = h23.x + sp[2];
        tv[3] = h23.y + sp[3]; tv[4] = h45.x + sp[4]; tv[5] = h45.y + sp[5];
        float o[HID];
#pragma unroll
        for (int dd = 0; dd < HID; ++dd) o[dd] = sb[dd];
#pragma unroll
        for (int k = 0; k < HID; ++k)
#pragma unroll
            for (int dd = 0; dd < HID; ++dd) o[dd] += tv[k] * sW[k * HID + dd];
#pragma unroll
        for (int dd = 0; dd < HID; ++dd) o[dd] = fmaxf(o[dd], 0.f);   // relu
        uint4 ov;
        ov.x = pk2(o[0], o[1]); ov.y = pk2(o[2], o[3]); ov.z = pk2(o[4], o[5]); ov.w = 0;
        out16[i] = ov;
    }
}

__global__ void __launch_bounds__(LTB) layerB3_pool_kernel(
        const uint4* __restrict__ h16,
        const uint4* __restrict__ mbin,
        const int* __restrict__ gcursorD,
        const float* __restrict__ W, const float* __restrict__ b,
        const int* __restrict__ batch,
        float* __restrict__ sums, float* __restrict__ cnts,
        int N, int capD) {
    __shared__ float sagg[BN * HID];     // 48 KB
    __shared__ float sW[HID * HID];
    __shared__ float sb[HID];
    int t = threadIdx.x;
    int bk = blockIdx.x;
    if (t < HID * HID) sW[t] = W[t];
    if (t < HID) sb[t] = b[t];
    for (int i = t; i < BN * HID; i += LTB) sagg[i] = 0.f;
    __syncthreads();

    long kbeg = (long)bk * capD;
    int cnt = gcursorD[bk] - (int)kbeg;
    accum_m(sagg, mbin, kbeg, cnt, t);
    __syncthreads();

    int nodeBase = bk << BSH;
    int lane = t & 63;
    for (int n = t; n < BN; n += LTB) {
        int i = nodeBase + n;
        bool active = (i < N);
        float o[HID];
        int g = -1;
        if (active) {
            uint4 hv = h16[i];
            float2 h01 = up2(hv.x), h23 = up2(hv.y), h45 = up2(hv.z);
            const float* sp = sagg + (size_t)n * HID;
            float tv[HID];
            tv[0] = h01.x + sp[0]; tv[1] = h01.y + sp[1]; tv[2] = h23.x + sp[2];
            tv[3] = h23.y + sp[3]; tv[4] = h45.x + sp[4]; tv[5] = h45.y + sp[5];
#pragma unroll
            for (int dd = 0; dd < HID; ++dd) o[dd] = sb[dd];
#pragma unroll
            for (int k = 0; k < HID; ++k)
#pragma unroll
                for (int dd = 0; dd < HID; ++dd) o[dd] += tv[k] * sW[k * HID + dd];
            g = batch[i];
        } else {
#pragma unroll
            for (int dd = 0; dd < HID; ++dd) o[dd] = 0.f;
        }
        int g0 = __shfl(g, 0);
        bool uniform = __all(active) && __all(g == g0);
        if (uniform) {
#pragma unroll
            for (int dd = 0; dd < HID; ++dd) {
                float s = o[dd];
                for (int off2 = 32; off2 > 0; off2 >>= 1) s += __shfl_down(s, off2);
                if (lane == 0) atomicAdd(&sums[(size_t)g0 * HID + dd], s);
            }
            if (lane == 0) atomicAdd(&cnts[g0], 64.0f);
        } else if (active) {
#pragma unroll
            for (int dd = 0; dd < HID; ++dd) atomicAdd(&sums[(size_t)g * HID + dd], o[dd]);
            atomicAdd(&cnts[g], 1.0f);
        }
    }
}

// ===========================================================================
// tier D fallback (fp16 h)
// ===========================================================================
__global__ void edge_kernel(const uint4* __restrict__ h16, const float* __restrict__ edge_attr,
                            const int* __restrict__ src, const int* __restrict__ dst,
                            float* __restrict__ agg, int E) {
    long e = (long)blockIdx.x * blockDim.x + threadIdx.x;
    if (e >= E) return;
    int s = src[e], d = dst[e];
    const float2* ea = (const float2*)(edge_attr + (size_t)e * HID);
    uint4 hv = h16[s];
    float2 h01 = up2(hv.x), h23 = up2(hv.y), h45 = up2(hv.z);
    float2 a0 = ea[0], a1 = ea[1], a2 = ea[2];
    float* ag = agg + (size_t)d * HID;
    atomicAdd(ag + 0, fmaxf(h01.x + a0.x, 0.f));
    atomicAdd(ag + 1, fmaxf(h01.y + a0.y, 0.f));
    atomicAdd(ag + 2, fmaxf(h23.x + a1.x, 0.f));
    atomicAdd(ag + 3, fmaxf(h23.y + a1.y, 0.f));
    atomicAdd(ag + 4, fmaxf(h45.x + a2.x, 0.f));
    atomicAdd(ag + 5, fmaxf(h45.y + a2.y, 0.f));
}

__global__ void node_kernel(const uint4* __restrict__ h16, const float* __restrict__ agg,
                            const float* __restrict__ W, const float* __restrict__ b,
                            uint4* __restrict__ out16, int N, int do_relu) {
    __shared__ float sW[HID * HID];
    __shared__ float sb[HID];
    if (threadIdx.x < HID * HID) sW[threadIdx.x] = W[threadIdx.x];
    if (threadIdx.x < HID) sb[threadIdx.x] = b[threadIdx.x];
    __syncthreads();
    int i = blockIdx.x * blockDim.x + threadIdx.x;
    if (i >= N) return;
    uint4 hv = h16[i];
    float2 h01 = up2(hv.x), h23 = up2(hv.y), h45 = up2(hv.z);
    const float2* ap = (const float2*)(agg + (size_t)i * HID);
    float2 g0 = ap[0], g1 = ap[1], g2 = ap[2];
    float tv[HID];
    tv[0] = h01.x + g0.x; tv[1] = h01.y + g0.y;
    tv[2] = h23.x + g1.x; tv[3] = h23.y + g1.y;
    tv[4] = h45.x + g2.x; tv[5] = h45.y + g2.y;
    float o[HID];
#pragma unroll
    for (int d = 0; d < HID; ++d) o[d] = sb[d];
#pragma unroll
    for (int k = 0; k < HID; ++k)
#pragma unroll
        for (int d = 0; d < HID; ++d) o[d] += tv[k] * sW[k * HID + d];
    if (do_relu)
#pragma unroll
        for (int d = 0; d < HID; ++d) o[d] = fmaxf(o[d], 0.f);
    uint4 ov;
    ov.x = pk2(o[0], o[1]); ov.y = pk2(o[2], o[3]); ov.z = pk2(o[4], o[5]); ov.w = 0;
    out16[i] = ov;
}

__global__ void pool_kernel(const uint4* __restrict__ h16, const int* __restrict__ batch,
                            float* __restrict__ sums, float* __restrict__ cnts, int N) {
    int i = blockIdx.x * blockDim.x + threadIdx.x;
    int lane = threadIdx.x & 63;
    bool active = (i < N);
    float v[HID];
    int g = -1;
    if (active) {
        g = batch[i];
        uint4 hv = h16[i];
        float2 h01 = up2(hv.x), h23 = up2(hv.y), h45 = up2(hv.z);
        v[0] = h01.x; v[1] = h01.y; v[2] = h23.x; v[3] = h23.y; v[4] = h45.x; v[5] = h45.y;
    } else {
#pragma unroll
        for (int d = 0; d < HID; ++d) v[d] = 0.0f;
    }
    int g0 = __shfl(g, 0);
    bool uniform = __all(active) && __all(g == g0);
    if (uniform) {
#pragma unroll
        for (int d = 0; d < HID; ++d) {
            float s = v[d];
            for (int off = 32; off > 0; off >>= 1) s += __shfl_down(s, off);
            if (lane == 0) atomicAdd(&sums[(size_t)g0 * HID + d], s);
        }
        if (lane == 0) atomicAdd(&cnts[g0], 64.0f);
    } else if (active) {
#pragma unroll
        for (int d = 0; d < HID; ++d) atomicAdd(&sums[(size_t)g * HID + d], v[d]);
        atomicAdd(&cnts[g], 1.0f);
    }
}

__global__ void out_kernel(const float* __restrict__ sums, const float* __restrict__ cnts,
                           const float* __restrict__ Wl, const float* __restrict__ bl,
                           float* __restrict__ out) {
    int gI = blockIdx.x * blockDim.x + threadIdx.x;
    if (gI >= NUM_GRAPHS) return;
    float c = fmaxf(cnts[gI], 1.0f);
    float acc = bl[0];
#pragma unroll
    for (int d = 0; d < HID; ++d) acc += (sums[(size_t)gI * HID + d] / c) * Wl[d];
    out[gI] = acc;
}

// ===========================================================================
extern "C" void kernel_launch(void* const* d_in, const int* in_sizes, int n_in,
                              void* d_out, int out_size, void* d_ws, size_t ws_size,
                              hipStream_t stream) {
    const float* x         = (const float*)d_in[0];
    const int*   eidx      = (const int*)d_in[1];
    const float* edge_attr = (const float*)d_in[2];
    const int*   batch     = (const int*)d_in[3];
    const float* W1 = (const float*)d_in[4];
    const float* b1 = (const float*)d_in[5];
    const float* W2 = (const float*)d_in[6];
    const float* b2 = (const float*)d_in[7];
    const float* W3 = (const float*)d_in[8];
    const float* b3 = (const float*)d_in[9];
    const float* Wl = (const float*)d_in[10];
    const float* bl = (const float*)d_in[11];

    const int N = in_sizes[0] / HID;
    const int E = in_sizes[1] / 2;
    const int* src = eidx;
    const int* dst = eidx + E;

    const int TB = 256;
    const int nbl = (N + TB - 1) / TB;
    const int ebl = (E + TB - 1) / TB;
    const int pbl = (E + CHUNK - 1) / CHUNK;

    const int NB = (N + BN - 1) >> BSH;               // 489 buckets (both sides)
    // capS: multiple of CHUNK, >= mean + ~20 sigma
    const int chpr = (E / (NB > 0 ? NB : 1) + CHUNK + CHUNK - 1) / CHUNK;
    const int capS = chpr * CHUNK;
    const int capD = ((E / (NB > 0 ? NB : 1)) + 3072 + 1023) & ~1023;
    const long slotsS = (long)NB * capS + 64;
    const long slotsD = (long)NB * capD + 64;

    char* w = (char*)d_ws;
    size_t off = 0;
    auto alloc = [&](size_t bytes) { void* p = w + off; off += (bytes + 255) & ~(size_t)255; return p; };

    uint4* hX   = (uint4*)alloc((size_t)N * sizeof(uint4));   // 16MB
    uint4* hA   = (uint4*)alloc((size_t)N * sizeof(uint4));   // 16MB
    float* sums = (float*)alloc((size_t)NUM_GRAPHS * HID * sizeof(float));
    float* cnts = (float*)alloc((size_t)NUM_GRAPHS * sizeof(float));
    size_t tierDneed = off + (size_t)N * sizeof(uint4)        // hB
                     + (size_t)N * HID * sizeof(float);       // agg

    uint4* srcbin   = (uint4*)alloc((size_t)slotsS * sizeof(uint4));  // ~216MB
    uint4* mbin     = (uint4*)alloc((size_t)slotsD * sizeof(uint4));  // ~224MB
    int*   gcursorS = (int*)alloc((size_t)NB * sizeof(int));
    int*   gcursorD = (int*)alloc((size_t)NB * sizeof(int));
    size_t tierAneed = off;

    pad_kernel<<<nbl, TB, 0, stream>>>(x, hX, N);
    hipMemsetAsync(sums, 0, (size_t)NUM_GRAPHS * HID * sizeof(float), stream);
    hipMemsetAsync(cnts, 0, (size_t)NUM_GRAPHS * sizeof(float), stream);

    const int icb = (NB + TB - 1) / TB;

    if (NB <= MAXNB && N <= (1 << 20) && ws_size >= tierAneed) {
        // ---- one-time: bin edges by src bucket ----
        init_cursor_kernel<<<icb, TB, 0, stream>>>(gcursorS, NB, capS);
        prep_kernel<<<pbl, TB, 0, stream>>>(src, dst, edge_attr, gcursorS, srcbin, E, capS, NB);

        // ---- layer 1: hX -> hA ----
        init_cursor_kernel<<<icb, TB, 0, stream>>>(gcursorD, NB, capD);
        layerA_kernel<<<NB * chpr, TB, 0, stream>>>(hX, srcbin, gcursorS, gcursorD, mbin,
                                                    capS, chpr, NB);
        layerB_kernel<<<NB, LTB, 0, stream>>>(hX, mbin, gcursorD, W1, b1, hA, N, capD);

        // ---- layer 2: hA -> hX (reuse) ----
        init_cursor_kernel<<<icb, TB, 0, stream>>>(gcursorD, NB, capD);
        layerA_kernel<<<NB * chpr, TB, 0, stream>>>(hA, srcbin, gcursorS, gcursorD, mbin,
                                                    capS, chpr, NB);
        layerB_kernel<<<NB, LTB, 0, stream>>>(hA, mbin, gcursorD, W2, b2, hX, N, capD);

        // ---- layer 3 + pool: hX -> sums/cnts ----
        init_cursor_kernel<<<icb, TB, 0, stream>>>(gcursorD, NB, capD);
        layerA_kernel<<<NB * chpr, TB, 0, stream>>>(hX, srcbin, gcursorS, gcursorD, mbin,
                                                    capS, chpr, NB);
        layerB3_pool_kernel<<<NB, LTB, 0, stream>>>(hX, mbin, gcursorD, W3, b3,
                                                    batch, sums, cnts, N, capD);
    } else {
        // ---- tier D: atomic fallback ----
        uint4* hB  = (uint4*)((char*)w + tierDneed - (size_t)N * HID * sizeof(float)
                              - (size_t)N * sizeof(uint4));
        float* agg = (float*)((char*)w + tierDneed - (size_t)N * HID * sizeof(float));
        const size_t szAgg = (size_t)N * HID * sizeof(float);
        hipMemsetAsync(agg, 0, szAgg, stream);
        edge_kernel<<<ebl, TB, 0, stream>>>(hX, edge_attr, src, dst, agg, E);
        node_kernel<<<nbl, TB, 0, stream>>>(hX, agg, W1, b1, hA, N, 1);
        hipMemsetAsync(agg, 0, szAgg, stream);
        edge_kernel<<<ebl, TB, 0, stream>>>(hA, edge_attr, src, dst, agg, E);
        node_kernel<<<nbl, TB, 0, stream>>>(hA, agg, W2, b2, hB, N, 1);
        hipMemsetAsync(agg, 0, szAgg, stream);
        edge_kernel<<<ebl, TB, 0, stream>>>(hB, edge_attr, src, dst, agg, E);
        node_kernel<<<nbl, TB, 0, stream>>>(hB, agg, W3, b3, hA, N, 0);
        pool_kernel<<<nbl, TB, 0, stream>>>(hA, batch, sums, cnts, N);
    }

    out_kernel<<<(NUM_GRAPHS + TB - 1) / TB, TB, 0, stream>>>(sums, cnts, Wl, bl, (float*)d_out);
}

// Round 15
// 1065.648 us; speedup vs baseline: 1.8581x; 1.8581x over previous
//
#include <hip/hip_runtime.h>
#include <hip/hip_fp16.h>

#define HID 6
#define NUM_GRAPHS 1000
#define BSH 11
#define BN (1 << BSH)           // 2048 nodes per bucket (src AND dst)
#define MAXNB 512
#define CHUNK 3072
#define PERT  12                // CHUNK / 256 (256-thread kernels)
#define LTB 1024
#define PERTB 3                 // CHUNK / LTB (layerB)

__device__ __forceinline__ unsigned pk2(float a, float b) {
    __half2 h = __floats2half2_rn(a, b);
    return *(unsigned*)&h;
}
__device__ __forceinline__ float2 up2(unsigned u) {
    __half2 h = *(__half2*)&u;
    return __half22float2(h);
}
__device__ __forceinline__ uint4 ldnt16(const uint4* p) {
    const unsigned long long* q = (const unsigned long long*)p;
    unsigned long long lo = __builtin_nontemporal_load(q);
    unsigned long long hi = __builtin_nontemporal_load(q + 1);
    uint4 r;
    r.x = (unsigned)lo; r.y = (unsigned)(lo >> 32);
    r.z = (unsigned)hi; r.w = (unsigned)(hi >> 32);
    return r;
}

// ===========================================================================
__global__ void pad_kernel(const float* __restrict__ x, uint4* __restrict__ h16, int N) {
    int i = blockIdx.x * blockDim.x + threadIdx.x;
    if (i >= N) return;
    const float2* s = (const float2*)(x + (size_t)i * HID);
    float2 a = s[0], b = s[1], c = s[2];
    uint4 o;
    o.x = pk2(a.x, a.y); o.y = pk2(b.x, b.y); o.z = pk2(c.x, c.y); o.w = 0;
    h16[i] = o;
}

__global__ void init_cursor_kernel(int* __restrict__ cur, int NB, int cap) {
    int b = blockIdx.x * blockDim.x + threadIdx.x;
    if (b < NB) cur[b] = b * cap;
}

// ===========================================================================
// prep (once): bin edges by src-bucket. record {ea fp16 x6, dst<<11 | srcLow11}
// ===========================================================================
__global__ void __launch_bounds__(256) prep_kernel(
        const int* __restrict__ src, const int* __restrict__ dst,
        const float* __restrict__ ea,
        int* __restrict__ gcursorS,
        uint4* __restrict__ srcbin,
        int E, int capS, int NBs) {
    __shared__ uint4 pay[CHUNK];                     // 48 KB
    __shared__ unsigned short sb_[CHUNK];            // 6 KB
    __shared__ int hist[MAXNB], cnt[MAXNB], base[MAXNB], lofs[MAXNB], pairs[256];

    int t = threadIdx.x;
    long e0 = (long)blockIdx.x * CHUNK;
    long rem = (long)E - e0;
    int count = (int)(rem < CHUNK ? rem : CHUNK);

    for (int b = t; b < MAXNB; b += 256) { hist[b] = 0; cnt[b] = 0; }
    __syncthreads();

    int s_[PERT], d_[PERT];
#pragma unroll
    for (int j = 0; j < PERT; ++j) {
        int le = t + j * 256;
        if (le < count) {
            s_[j] = src[e0 + le];
            d_[j] = dst[e0 + le];
            atomicAdd(&hist[s_[j] >> BSH], 1);
        } else { s_[j] = -1; }
    }
    __syncthreads();

    {   // scan hist[0..512) -> lofs
        int b0 = 2 * t, b1 = 2 * t + 1;
        int s0 = hist[b0], s1 = hist[b1];
        pairs[t] = s0 + s1;
        __syncthreads();
        for (int off = 1; off < 256; off <<= 1) {
            int a = (t >= off) ? pairs[t - off] : 0;
            __syncthreads();
            pairs[t] += a;
            __syncthreads();
        }
        int excl = (t == 0) ? 0 : pairs[t - 1];
        lofs[b0] = excl;
        lofs[b1] = excl + s0;
    }
    for (int b = t; b < NBs; b += 256) {
        int c = hist[b];
        base[b] = c ? atomicAdd(&gcursorS[b], c) : 0;
    }
    __syncthreads();

#pragma unroll
    for (int j = 0; j < PERT; ++j) {
        if (s_[j] < 0) continue;
        int b = s_[j] >> BSH;
        long e = e0 + (t + j * 256);
        const float2* ep = (const float2*)(ea + (size_t)e * HID);
        float2 A = ep[0], B = ep[1], C = ep[2];
        uint4 p;
        p.x = pk2(A.x, A.y);
        p.y = pk2(B.x, B.y);
        p.z = pk2(C.x, C.y);
        p.w = ((unsigned)d_[j] << BSH) | (unsigned)(s_[j] & (BN - 1));
        int r = atomicAdd(&cnt[b], 1);
        int slot = lofs[b] + r;
        pay[slot] = p;
        sb_[slot] = (unsigned short)b;
    }
    __syncthreads();

    for (int s2 = t; s2 < count; s2 += 256) {
        int b = sb_[s2];
        long gpos = (long)base[b] + (s2 - lofs[b]);
        srcbin[gpos] = pay[s2];
    }
}

// ===========================================================================
// layer A: per src-bucket chunk, compute m = relu(h[src]+ea) (h from 32KB
// L1-resident window) and LDS-bin m-records by dst bucket.
// out record: {m fp16 x6, dloc11}
// ===========================================================================
__global__ void __launch_bounds__(256) layerA_kernel(
        const uint4* __restrict__ h16,
        const uint4* __restrict__ srcbin,
        const int* __restrict__ gcursorS,
        int* __restrict__ gcursorD,
        uint4* __restrict__ mbin,
        int capS, int chpr, int NBd) {
    __shared__ uint4 pay[CHUNK];                     // 48 KB
    __shared__ unsigned short sb_[CHUNK];            // 6 KB
    __shared__ int hist[MAXNB], cnt2[MAXNB], base[MAXNB], lofs[MAXNB], pairs[256];

    int t = threadIdx.x;
    int sreg = blockIdx.x / chpr;
    int ci   = blockIdx.x % chpr;
    int regCnt = gcursorS[sreg] - sreg * capS;
    int count = regCnt - ci * CHUNK;
    if (count <= 0) return;                          // uniform per block
    if (count > CHUNK) count = CHUNK;
    long m0 = (long)sreg * capS + (long)ci * CHUNK;
    int sbase = sreg << BSH;

    for (int b = t; b < MAXNB; b += 256) { hist[b] = 0; cnt2[b] = 0; }
    __syncthreads();

    uint4 r_[PERT];
    int bk_[PERT];
#pragma unroll
    for (int j = 0; j < PERT; ++j) {
        int le = t + j * 256;
        if (le < count) {
            uint4 rec = ldnt16(srcbin + m0 + le);
            int s = sbase | (rec.w & (BN - 1));
            unsigned dd = rec.w >> BSH;
            uint4 hv = h16[s];                        // 32KB window -> L1
            float2 e01 = up2(rec.x), e23 = up2(rec.y), e45 = up2(rec.z);
            float2 h01 = up2(hv.x),  h23 = up2(hv.y),  h45 = up2(hv.z);
            uint4 o;
            o.x = pk2(fmaxf(h01.x + e01.x, 0.f), fmaxf(h01.y + e01.y, 0.f));
            o.y = pk2(fmaxf(h23.x + e23.x, 0.f), fmaxf(h23.y + e23.y, 0.f));
            o.z = pk2(fmaxf(h45.x + e45.x, 0.f), fmaxf(h45.y + e45.y, 0.f));
            o.w = dd & (BN - 1);                      // dloc
            r_[j] = o;
            bk_[j] = dd >> BSH;
            atomicAdd(&hist[bk_[j]], 1);
        } else bk_[j] = -1;
    }
    __syncthreads();

    {   // scan hist[0..512) -> lofs
        int b0 = 2 * t, b1 = 2 * t + 1;
        int s0 = hist[b0], s1 = hist[b1];
        pairs[t] = s0 + s1;
        __syncthreads();
        for (int off = 1; off < 256; off <<= 1) {
            int a = (t >= off) ? pairs[t - off] : 0;
            __syncthreads();
            pairs[t] += a;
            __syncthreads();
        }
        int excl = (t == 0) ? 0 : pairs[t - 1];
        lofs[b0] = excl;
        lofs[b1] = excl + s0;
    }
    for (int b = t; b < NBd; b += 256) {
        int c = hist[b];
        base[b] = c ? atomicAdd(&gcursorD[b], c) : 0;
    }
    __syncthreads();

#pragma unroll
    for (int j = 0; j < PERT; ++j) {
        if (bk_[j] < 0) continue;
        int b = bk_[j];
        int r = atomicAdd(&cnt2[b], 1);
        int slot = lofs[b] + r;
        pay[slot] = r_[j];
        sb_[slot] = (unsigned short)b;
    }
    __syncthreads();

    for (int s2 = t; s2 < count; s2 += 256) {
        int b = sb_[s2];
        long gpos = (long)base[b] + (s2 - lofs[b]);
        mbin[gpos] = pay[s2];
    }
}

// ===========================================================================
// layer B (owner-computes): per chunk build dloc-CSR in LDS; thread t owns
// dlocs {2t, 2t+1} and accumulates into registers. No accumulation atomics.
// ACC_BODY defines the epilogue.
// ===========================================================================
#define LAYERB_CORE                                                           \
    __shared__ uint4 pay[CHUNK];            /* 48 KB */                       \
    __shared__ unsigned short slot[CHUNK];  /* 6 KB */                        \
    __shared__ int hist[BN];                /* 8 KB */                        \
    __shared__ int wsum[16];                                                  \
    int t = threadIdx.x;                                                      \
    int lane = t & 63, wid = t >> 6;                                          \
    int bk = blockIdx.x;                                                      \
    long kbeg = (long)bk * capD;                                              \
    int cnt = gcursorD[bk] - (int)kbeg;                                       \
    float a00 = 0.f, a01 = 0.f, a02 = 0.f, a03 = 0.f, a04 = 0.f, a05 = 0.f;   \
    float a10 = 0.f, a11 = 0.f, a12 = 0.f, a13 = 0.f, a14 = 0.f, a15 = 0.f;   \
    for (int c0 = 0; c0 < cnt; c0 += CHUNK) {                                 \
        int cc = cnt - c0; if (cc > CHUNK) cc = CHUNK;                        \
        hist[2 * t] = 0; hist[2 * t + 1] = 0;                                 \
        __syncthreads();                                                      \
        int dl_[PERTB];                                                       \
        _Pragma("unroll")                                                     \
        for (int j = 0; j < PERTB; ++j) {                                     \
            int le = t + j * LTB;                                             \
            if (le < cc) {                                                    \
                uint4 p = ldnt16(mbin + kbeg + c0 + le);                      \
                pay[le] = p;                                                  \
                dl_[j] = p.w & (BN - 1);                                      \
                atomicAdd(&hist[dl_[j]], 1);                                  \
            } else dl_[j] = -1;                                               \
        }                                                                     \
        __syncthreads();                                                      \
        int s0 = hist[2 * t], s1 = hist[2 * t + 1];                           \
        int v = s0 + s1;                                                      \
        int w = v;                                                            \
        _Pragma("unroll")                                                     \
        for (int o2 = 1; o2 < 64; o2 <<= 1) {                                 \
            int u = __shfl_up(w, o2, 64);                                     \
            if (lane >= o2) w += u;                                           \
        }                                                                     \
        if (lane == 63) wsum[wid] = w;                                        \
        __syncthreads();                                                      \
        if (wid == 0) {                                                       \
            int sv = (lane < 16) ? wsum[lane] : 0;                            \
            int ws = sv;                                                      \
            _Pragma("unroll")                                                 \
            for (int o2 = 1; o2 < 16; o2 <<= 1) {                             \
                int u = __shfl_up(ws, o2, 64);                                \
                if (lane >= o2) ws += u;                                      \
            }                                                                 \
            if (lane < 16) wsum[lane] = ws - sv;                              \
        }                                                                     \
        __syncthreads();                                                      \
        int start0 = wsum[wid] + (w - v);                                     \
        int start1 = start0 + s0;                                             \
        hist[2 * t] = start0; hist[2 * t + 1] = start1;                       \
        __syncthreads();                                                      \
        _Pragma("unroll")                                                     \
        for (int j = 0; j < PERTB; ++j) {                                     \
            if (dl_[j] < 0) continue;                                         \
            int sl = atomicAdd(&hist[dl_[j]], 1);                             \
            slot[sl] = (unsigned short)(t + j * LTB);                         \
        }                                                                     \
        __syncthreads();                                                      \
        for (int k = 0; k < s0; ++k) {                                        \
            uint4 p = pay[slot[start0 + k]];                                  \
            float2 m01 = up2(p.x), m23 = up2(p.y), m45 = up2(p.z);            \
            a00 += m01.x; a01 += m01.y; a02 += m23.x;                         \
            a03 += m23.y; a04 += m45.x; a05 += m45.y;                         \
        }                                                                     \
        for (int k = 0; k < s1; ++k) {                                        \
            uint4 p = pay[slot[start1 + k]];                                  \
            float2 m01 = up2(p.x), m23 = up2(p.y), m45 = up2(p.z);            \
            a10 += m01.x; a11 += m01.y; a12 += m23.x;                         \
            a13 += m23.y; a14 += m45.x; a15 += m45.y;                         \
        }                                                                     \
        __syncthreads();                                                      \
    }                                                                         \
    __shared__ float sW[HID * HID];                                           \
    __shared__ float sb[HID];                                                 \
    if (t < HID * HID) sW[t] = W[t];                                          \
    if (t < HID) sb[t] = b[t];                                                \
    __syncthreads();                                                          \
    int nodeBase = bk << BSH;

#define NODE_MM(TV, O)                                                        \
    float O[HID];                                                             \
    _Pragma("unroll")                                                         \
    for (int dd = 0; dd < HID; ++dd) O[dd] = sb[dd];                          \
    _Pragma("unroll")                                                         \
    for (int kk = 0; kk < HID; ++kk)                                          \
        _Pragma("unroll")                                                     \
        for (int dd = 0; dd < HID; ++dd) O[dd] += TV[kk] * sW[kk * HID + dd];

__global__ void __launch_bounds__(LTB) layerB_kernel(
        const uint4* __restrict__ h16,
        const uint4* __restrict__ mbin,
        const int* __restrict__ gcursorD,
        const float* __restrict__ W, const float* __restrict__ b,
        uint4* __restrict__ out16, int N, int capD) {
    LAYERB_CORE
    // epilogue: nodes 2t, 2t+1 (relu)
    {
        int i = nodeBase + 2 * t;
        if (i < N) {
            uint4 hv = h16[i];
            float2 h01 = up2(hv.x), h23 = up2(hv.y), h45 = up2(hv.z);
            float tv[HID] = {h01.x + a00, h01.y + a01, h23.x + a02,
                             h23.y + a03, h45.x + a04, h45.y + a05};
            NODE_MM(tv, o)
#pragma unroll
            for (int dd = 0; dd < HID; ++dd) o[dd] = fmaxf(o[dd], 0.f);
            uint4 ov;
            ov.x = pk2(o[0], o[1]); ov.y = pk2(o[2], o[3]); ov.z = pk2(o[4], o[5]); ov.w = 0;
            out16[i] = ov;
        }
        i = nodeBase + 2 * t + 1;
        if (i < N) {
            uint4 hv = h16[i];
            float2 h01 = up2(hv.x), h23 = up2(hv.y), h45 = up2(hv.z);
            float tv[HID] = {h01.x + a10, h01.y + a11, h23.x + a12,
                             h23.y + a13, h45.x + a14, h45.y + a15};
            NODE_MM(tv, o)
#pragma unroll
            for (int dd = 0; dd < HID; ++dd) o[dd] = fmaxf(o[dd], 0.f);
            uint4 ov;
            ov.x = pk2(o[0], o[1]); ov.y = pk2(o[2], o[3]); ov.z = pk2(o[4], o[5]); ov.w = 0;
            out16[i] = ov;
        }
    }
}

__global__ void __launch_bounds__(LTB) layerB3_pool_kernel(
        const uint4* __restrict__ h16,
        const uint4* __restrict__ mbin,
        const int* __restrict__ gcursorD,
        const float* __restrict__ W, const float* __restrict__ b,
        const int* __restrict__ batch,
        float* __restrict__ sums, float* __restrict__ cnts,
        int N, int capD) {
    LAYERB_CORE
    // epilogue: nodes 2t, 2t+1 (no relu) + pool accumulate
#pragma unroll
    for (int jj = 0; jj < 2; ++jj) {
        int i = nodeBase + 2 * t + jj;
        bool active = (i < N);
        float o[HID];
        int g = -1;
        if (active) {
            uint4 hv = h16[i];
            float2 h01 = up2(hv.x), h23 = up2(hv.y), h45 = up2(hv.z);
            float tv[HID];
            if (jj == 0) {
                tv[0] = h01.x + a00; tv[1] = h01.y + a01; tv[2] = h23.x + a02;
                tv[3] = h23.y + a03; tv[4] = h45.x + a04; tv[5] = h45.y + a05;
            } else {
                tv[0] = h01.x + a10; tv[1] = h01.y + a11; tv[2] = h23.x + a12;
                tv[3] = h23.y + a13; tv[4] = h45.x + a14; tv[5] = h45.y + a15;
            }
#pragma unroll
            for (int dd = 0; dd < HID; ++dd) o[dd] = sb[dd];
#pragma unroll
            for (int kk = 0; kk < HID; ++kk)
#pragma unroll
                for (int dd = 0; dd < HID; ++dd) o[dd] += tv[kk] * sW[kk * HID + dd];
            g = batch[i];
        } else {
#pragma unroll
            for (int dd = 0; dd < HID; ++dd) o[dd] = 0.f;
        }
        int g0 = __shfl(g, 0);
        bool uniform = __all(active) && __all(g == g0);
        if (uniform) {
#pragma unroll
            for (int dd = 0; dd < HID; ++dd) {
                float s = o[dd];
                for (int off2 = 32; off2 > 0; off2 >>= 1) s += __shfl_down(s, off2);
                if (lane == 0) atomicAdd(&sums[(size_t)g0 * HID + dd], s);
            }
            if (lane == 0) atomicAdd(&cnts[g0], 64.0f);
        } else if (active) {
#pragma unroll
            for (int dd = 0; dd < HID; ++dd) atomicAdd(&sums[(size_t)g * HID + dd], o[dd]);
            atomicAdd(&cnts[g], 1.0f);
        }
    }
}

// ===========================================================================
// tier D fallback (fp16 h)
// ===========================================================================
__global__ void edge_kernel(const uint4* __restrict__ h16, const float* __restrict__ edge_attr,
                            const int* __restrict__ src, const int* __restrict__ dst,
                            float* __restrict__ agg, int E) {
    long e = (long)blockIdx.x * blockDim.x + threadIdx.x;
    if (e >= E) return;
    int s = src[e], d = dst[e];
    const float2* ea = (const float2*)(edge_attr + (size_t)e * HID);
    uint4 hv = h16[s];
    float2 h01 = up2(hv.x), h23 = up2(hv.y), h45 = up2(hv.z);
    float2 a0 = ea[0], a1 = ea[1], a2 = ea[2];
    float* ag = agg + (size_t)d * HID;
    atomicAdd(ag + 0, fmaxf(h01.x + a0.x, 0.f));
    atomicAdd(ag + 1, fmaxf(h01.y + a0.y, 0.f));
    atomicAdd(ag + 2, fmaxf(h23.x + a1.x, 0.f));
    atomicAdd(ag + 3, fmaxf(h23.y + a1.y, 0.f));
    atomicAdd(ag + 4, fmaxf(h45.x + a2.x, 0.f));
    atomicAdd(ag + 5, fmaxf(h45.y + a2.y, 0.f));
}

__global__ void node_kernel(const uint4* __restrict__ h16, const float* __restrict__ agg,
                            const float* __restrict__ W, const float* __restrict__ b,
                            uint4* __restrict__ out16, int N, int do_relu) {
    __shared__ float sW[HID * HID];
    __shared__ float sb[HID];
    if (threadIdx.x < HID * HID) sW[threadIdx.x] = W[threadIdx.x];
    if (threadIdx.x < HID) sb[threadIdx.x] = b[threadIdx.x];
    __syncthreads();
    int i = blockIdx.x * blockDim.x + threadIdx.x;
    if (i >= N) return;
    uint4 hv = h16[i];
    float2 h01 = up2(hv.x), h23 = up2(hv.y), h45 = up2(hv.z);
    const float2* ap = (const float2*)(agg + (size_t)i * HID);
    float2 g0 = ap[0], g1 = ap[1], g2 = ap[2];
    float tv[HID];
    tv[0] = h01.x + g0.x; tv[1] = h01.y + g0.y;
    tv[2] = h23.x + g1.x; tv[3] = h23.y + g1.y;
    tv[4] = h45.x + g2.x; tv[5] = h45.y + g2.y;
    float o[HID];
#pragma unroll
    for (int d = 0; d < HID; ++d) o[d] = sb[d];
#pragma unroll
    for (int k = 0; k < HID; ++k)
#pragma unroll
        for (int d = 0; d < HID; ++d) o[d] += tv[k] * sW[k * HID + d];
    if (do_relu)
#pragma unroll
        for (int d = 0; d < HID; ++d) o[d] = fmaxf(o[d], 0.f);
    uint4 ov;
    ov.x = pk2(o[0], o[1]); ov.y = pk2(o[2], o[3]); ov.z = pk2(o[4], o[5]); ov.w = 0;
    out16[i] = ov;
}

__global__ void pool_kernel(const uint4* __restrict__ h16, const int* __restrict__ batch,
                            float* __restrict__ sums, float* __restrict__ cnts, int N) {
    int i = blockIdx.x * blockDim.x + threadIdx.x;
    int lane = threadIdx.x & 63;
    bool active = (i < N);
    float v[HID];
    int g = -1;
    if (active) {
        g = batch[i];
        uint4 hv = h16[i];
        float2 h01 = up2(hv.x), h23 = up2(hv.y), h45 = up2(hv.z);
        v[0] = h01.x; v[1] = h01.y; v[2] = h23.x; v[3] = h23.y; v[4] = h45.x; v[5] = h45.y;
    } else {
#pragma unroll
        for (int d = 0; d < HID; ++d) v[d] = 0.0f;
    }
    int g0 = __shfl(g, 0);
    bool uniform = __all(active) && __all(g == g0);
    if (uniform) {
#pragma unroll
        for (int d = 0; d < HID; ++d) {
            float s = v[d];
            for (int off = 32; off > 0; off >>= 1) s += __shfl_down(s, off);
            if (lane == 0) atomicAdd(&sums[(size_t)g0 * HID + d], s);
        }
        if (lane == 0) atomicAdd(&cnts[g0], 64.0f);
    } else if (active) {
#pragma unroll
        for (int d = 0; d < HID; ++d) atomicAdd(&sums[(size_t)g * HID + d], v[d]);
        atomicAdd(&cnts[g], 1.0f);
    }
}

__global__ void out_kernel(const float* __restrict__ sums, const float* __restrict__ cnts,
                           const float* __restrict__ Wl, const float* __restrict__ bl,
                           float* __restrict__ out) {
    int gI = blockIdx.x * blockDim.x + threadIdx.x;
    if (gI >= NUM_GRAPHS) return;
    float c = fmaxf(cnts[gI], 1.0f);
    float acc = bl[0];
#pragma unroll
    for (int d = 0; d < HID; ++d) acc += (sums[(size_t)gI * HID + d] / c) * Wl[d];
    out[gI] = acc;
}

// ===========================================================================
extern "C" void kernel_launch(void* const* d_in, const int* in_sizes, int n_in,
                              void* d_out, int out_size, void* d_ws, size_t ws_size,
                              hipStream_t stream) {
    const float* x         = (const float*)d_in[0];
    const int*   eidx      = (const int*)d_in[1];
    const float* edge_attr = (const float*)d_in[2];
    const int*   batch     = (const int*)d_in[3];
    const float* W1 = (const float*)d_in[4];
    const float* b1 = (const float*)d_in[5];
    const float* W2 = (const float*)d_in[6];
    const float* b2 = (const float*)d_in[7];
    const float* W3 = (const float*)d_in[8];
    const float* b3 = (const float*)d_in[9];
    const float* Wl = (const float*)d_in[10];
    const float* bl = (const float*)d_in[11];

    const int N = in_sizes[0] / HID;
    const int E = in_sizes[1] / 2;
    const int* src = eidx;
    const int* dst = eidx + E;

    const int TB = 256;
    const int nbl = (N + TB - 1) / TB;
    const int ebl = (E + TB - 1) / TB;
    const int pbl = (E + CHUNK - 1) / CHUNK;

    const int NB = (N + BN - 1) >> BSH;               // 489 buckets (both sides)
    const int chpr = (E / (NB > 0 ? NB : 1) + CHUNK + CHUNK - 1) / CHUNK;
    const int capS = chpr * CHUNK;
    const int capD = ((E / (NB > 0 ? NB : 1)) + 3072 + 1023) & ~1023;
    const long slotsS = (long)NB * capS + 64;
    const long slotsD = (long)NB * capD + 64;

    char* w = (char*)d_ws;
    size_t off = 0;
    auto alloc = [&](size_t bytes) { void* p = w + off; off += (bytes + 255) & ~(size_t)255; return p; };

    uint4* hX   = (uint4*)alloc((size_t)N * sizeof(uint4));   // 16MB
    uint4* hA   = (uint4*)alloc((size_t)N * sizeof(uint4));   // 16MB
    float* sums = (float*)alloc((size_t)NUM_GRAPHS * HID * sizeof(float));
    float* cnts = (float*)alloc((size_t)NUM_GRAPHS * sizeof(float));
    size_t tierDneed = off + (size_t)N * sizeof(uint4)        // hB
                     + (size_t)N * HID * sizeof(float);       // agg

    uint4* srcbin   = (uint4*)alloc((size_t)slotsS * sizeof(uint4));  // ~216MB
    uint4* mbin     = (uint4*)alloc((size_t)slotsD * sizeof(uint4));  // ~224MB
    int*   gcursorS = (int*)alloc((size_t)NB * sizeof(int));
    int*   gcursorD = (int*)alloc((size_t)NB * sizeof(int));
    size_t tierAneed = off;

    pad_kernel<<<nbl, TB, 0, stream>>>(x, hX, N);
    hipMemsetAsync(sums, 0, (size_t)NUM_GRAPHS * HID * sizeof(float), stream);
    hipMemsetAsync(cnts, 0, (size_t)NUM_GRAPHS * sizeof(float), stream);

    const int icb = (NB + TB - 1) / TB;

    if (NB <= MAXNB && N <= (1 << 20) && ws_size >= tierAneed) {
        // ---- one-time: bin edges by src bucket ----
        init_cursor_kernel<<<icb, TB, 0, stream>>>(gcursorS, NB, capS);
        prep_kernel<<<pbl, TB, 0, stream>>>(src, dst, edge_attr, gcursorS, srcbin, E, capS, NB);

        // ---- layer 1: hX -> hA ----
        init_cursor_kernel<<<icb, TB, 0, stream>>>(gcursorD, NB, capD);
        layerA_kernel<<<NB * chpr, TB, 0, stream>>>(hX, srcbin, gcursorS, gcursorD, mbin,
                                                    capS, chpr, NB);
        layerB_kernel<<<NB, LTB, 0, stream>>>(hX, mbin, gcursorD, W1, b1, hA, N, capD);

        // ---- layer 2: hA -> hX (reuse) ----
        init_cursor_kernel<<<icb, TB, 0, stream>>>(gcursorD, NB, capD);
        layerA_kernel<<<NB * chpr, TB, 0, stream>>>(hA, srcbin, gcursorS, gcursorD, mbin,
                                                    capS, chpr, NB);
        layerB_kernel<<<NB, LTB, 0, stream>>>(hA, mbin, gcursorD, W2, b2, hX, N, capD);

        // ---- layer 3 + pool: hX -> sums/cnts ----
        init_cursor_kernel<<<icb, TB, 0, stream>>>(gcursorD, NB, capD);
        layerA_kernel<<<NB * chpr, TB, 0, stream>>>(hX, srcbin, gcursorS, gcursorD, mbin,
                                                    capS, chpr, NB);
        layerB3_pool_kernel<<<NB, LTB, 0, stream>>>(hX, mbin, gcursorD, W3, b3,
                                                    batch, sums, cnts, N, capD);
    } else {
        // ---- tier D: atomic fallback ----
        uint4* hB  = (uint4*)((char*)w + tierDneed - (size_t)N * HID * sizeof(float)
                              - (size_t)N * sizeof(uint4));
        float* agg = (float*)((char*)w + tierDneed - (size_t)N * HID * sizeof(float));
        const size_t szAgg = (size_t)N * HID * sizeof(float);
        hipMemsetAsync(agg, 0, szAgg, stream);
        edge_kernel<<<ebl, TB, 0, stream>>>(hX, edge_attr, src, dst, agg, E);
        node_kernel<<<nbl, TB, 0, stream>>>(hX, agg, W1, b1, hA, N, 1);
        hipMemsetAsync(agg, 0, szAgg, stream);
        edge_kernel<<<ebl, TB, 0, stream>>>(hA, edge_attr, src, dst, agg, E);
        node_kernel<<<nbl, TB, 0, stream>>>(hA, agg, W2, b2, hB, N, 1);
        hipMemsetAsync(agg, 0, szAgg, stream);
        edge_kernel<<<ebl, TB, 0, stream>>>(hB, edge_attr, src, dst, agg, E);
        node_kernel<<<nbl, TB, 0, stream>>>(hB, agg, W3, b3, hA, N, 0);
        pool_kernel<<<nbl, TB, 0, stream>>>(hA, batch, sums, cnts, N);
    }

    out_kernel<<<(NUM_GRAPHS + TB - 1) / TB, TB, 0, stream>>>(sums, cnts, Wl, bl, (float*)d_out);
}

// Round 16
// 1007.043 us; speedup vs baseline: 1.9662x; 1.0582x over previous
//
#include <hip/hip_runtime.h>
#include <hip/hip_fp16.h>

#define HID 6
#define NUM_GRAPHS 1000
#define BSH 11
#define BN (1 << BSH)           // 2048 nodes per bucket (src AND dst)
#define MAXNB 512
#define CHUNK 3072
#define PERT  12                // CHUNK / 256 (256-thread kernels)
#define LTB 1024
#define PERTB 3                 // CHUNK / LTB (layerB)

__device__ __forceinline__ unsigned pk2(float a, float b) {
    __half2 h = __floats2half2_rn(a, b);
    return *(unsigned*)&h;
}
__device__ __forceinline__ float2 up2(unsigned u) {
    __half2 h = *(__half2*)&u;
    return __half22float2(h);
}
__device__ __forceinline__ uint4 ldnt16(const uint4* p) {
    const unsigned long long* q = (const unsigned long long*)p;
    unsigned long long lo = __builtin_nontemporal_load(q);
    unsigned long long hi = __builtin_nontemporal_load(q + 1);
    uint4 r;
    r.x = (unsigned)lo; r.y = (unsigned)(lo >> 32);
    r.z = (unsigned)hi; r.w = (unsigned)(hi >> 32);
    return r;
}

// ===========================================================================
__global__ void pad_kernel(const float* __restrict__ x, uint4* __restrict__ h16, int N) {
    int i = blockIdx.x * blockDim.x + threadIdx.x;
    if (i >= N) return;
    const float2* s = (const float2*)(x + (size_t)i * HID);
    float2 a = s[0], b = s[1], c = s[2];
    uint4 o;
    o.x = pk2(a.x, a.y); o.y = pk2(b.x, b.y); o.z = pk2(c.x, c.y); o.w = 0;
    h16[i] = o;
}

__global__ void init_cursor_kernel(int* __restrict__ cur, int NB, int cap) {
    int b = blockIdx.x * blockDim.x + threadIdx.x;
    if (b < NB) cur[b] = b * cap;
}

// ===========================================================================
// prep (once): bin edges by src-bucket. record {ea fp16 x6, dst<<11 | srcLow11}
// Vectorized fast path: 4 consecutive edges/thread (int4 src/dst, float4 ea).
// ===========================================================================
__global__ void __launch_bounds__(256) prep_kernel(
        const int* __restrict__ src, const int* __restrict__ dst,
        const float* __restrict__ ea,
        int* __restrict__ gcursorS,
        uint4* __restrict__ srcbin,
        int E, int capS, int NBs) {
    __shared__ uint4 pay[CHUNK];                     // 48 KB
    __shared__ unsigned short sb_[CHUNK];            // 6 KB
    __shared__ int hist[MAXNB], cnt[MAXNB], base[MAXNB], lofs[MAXNB], pairs[256];

    int t = threadIdx.x;
    long e0 = (long)blockIdx.x * CHUNK;
    long rem = (long)E - e0;
    int count = (int)(rem < CHUNK ? rem : CHUNK);
    bool fast = (count == CHUNK);

    for (int b = t; b < MAXNB; b += 256) { hist[b] = 0; cnt[b] = 0; }
    __syncthreads();

    // ---- phase 1: histogram ----
    int4 s4[3], d4[3];
    if (fast) {
#pragma unroll
        for (int j = 0; j < 3; ++j) {
            long e = e0 + ((long)(t + j * 256)) * 4;
            s4[j] = *(const int4*)(src + e);
            d4[j] = *(const int4*)(dst + e);
            atomicAdd(&hist[s4[j].x >> BSH], 1);
            atomicAdd(&hist[s4[j].y >> BSH], 1);
            atomicAdd(&hist[s4[j].z >> BSH], 1);
            atomicAdd(&hist[s4[j].w >> BSH], 1);
        }
    } else {
        for (int le = t; le < count; le += 256) atomicAdd(&hist[src[e0 + le] >> BSH], 1);
    }
    __syncthreads();

    // ---- phase 2a: exclusive scan of hist[0..512) -> lofs ----
    {
        int b0 = 2 * t, b1 = 2 * t + 1;
        int s0 = hist[b0], s1 = hist[b1];
        pairs[t] = s0 + s1;
        __syncthreads();
        for (int off = 1; off < 256; off <<= 1) {
            int a = (t >= off) ? pairs[t - off] : 0;
            __syncthreads();
            pairs[t] += a;
            __syncthreads();
        }
        int excl = (t == 0) ? 0 : pairs[t - 1];
        lofs[b0] = excl;
        lofs[b1] = excl + s0;
    }
    // ---- phase 2b: reserve global space per touched bucket ----
    for (int b = t; b < NBs; b += 256) {
        int c = hist[b];
        base[b] = c ? atomicAdd(&gcursorS[b], c) : 0;
    }
    __syncthreads();

    // ---- phase 3: pack + LDS scatter at slot ----
    if (fast) {
#pragma unroll
        for (int j = 0; j < 3; ++j) {
            long e = e0 + ((long)(t + j * 256)) * 4;
            const float4* ep = (const float4*)(ea + (size_t)e * HID);
            float4 f0 = ep[0], f1 = ep[1], f2 = ep[2], f3 = ep[3], f4 = ep[4], f5 = ep[5];
            int ss[4] = {s4[j].x, s4[j].y, s4[j].z, s4[j].w};
            int dd[4] = {d4[j].x, d4[j].y, d4[j].z, d4[j].w};
            uint4 rec[4];
            rec[0].x = pk2(f0.x, f0.y); rec[0].y = pk2(f0.z, f0.w); rec[0].z = pk2(f1.x, f1.y);
            rec[1].x = pk2(f1.z, f1.w); rec[1].y = pk2(f2.x, f2.y); rec[1].z = pk2(f2.z, f2.w);
            rec[2].x = pk2(f3.x, f3.y); rec[2].y = pk2(f3.z, f3.w); rec[2].z = pk2(f4.x, f4.y);
            rec[3].x = pk2(f4.z, f4.w); rec[3].y = pk2(f5.x, f5.y); rec[3].z = pk2(f5.z, f5.w);
#pragma unroll
            for (int k = 0; k < 4; ++k) {
                int b = ss[k] >> BSH;
                rec[k].w = ((unsigned)dd[k] << BSH) | (unsigned)(ss[k] & (BN - 1));
                int r = atomicAdd(&cnt[b], 1);
                int slot2 = lofs[b] + r;
                pay[slot2] = rec[k];
                sb_[slot2] = (unsigned short)b;
            }
        }
    } else {
        for (int le = t; le < count; le += 256) {
            long e = e0 + le;
            int s = src[e], dd = dst[e];
            int b = s >> BSH;
            const float2* ep = (const float2*)(ea + (size_t)e * HID);
            float2 A = ep[0], B = ep[1], C = ep[2];
            uint4 p;
            p.x = pk2(A.x, A.y);
            p.y = pk2(B.x, B.y);
            p.z = pk2(C.x, C.y);
            p.w = ((unsigned)dd << BSH) | (unsigned)(s & (BN - 1));
            int r = atomicAdd(&cnt[b], 1);
            int slot2 = lofs[b] + r;
            pay[slot2] = p;
            sb_[slot2] = (unsigned short)b;
        }
    }
    __syncthreads();

    // ---- phase 4: sequential LDS read -> contiguous global runs ----
    for (int s2 = t; s2 < count; s2 += 256) {
        int b = sb_[s2];
        long gpos = (long)base[b] + (s2 - lofs[b]);
        srcbin[gpos] = pay[s2];
    }
}

// ===========================================================================
// layer A: per src-bucket chunk, compute m = relu(h[src]+ea) (h from 32KB
// L1-resident window) and LDS-bin m-records by dst bucket.
// staged record carries full dst; bucket recovered in phase 4; out = dloc only.
// ===========================================================================
__global__ void __launch_bounds__(256) layerA_kernel(
        const uint4* __restrict__ h16,
        const uint4* __restrict__ srcbin,
        const int* __restrict__ gcursorS,
        int* __restrict__ gcursorD,
        uint4* __restrict__ mbin,
        int capS, int chpr, int NBd) {
    __shared__ uint4 pay[CHUNK];                     // 48 KB
    __shared__ int hist[MAXNB], cnt2[MAXNB], base[MAXNB], lofs[MAXNB], pairs[256];

    int t = threadIdx.x;
    int sreg = blockIdx.x / chpr;
    int ci   = blockIdx.x % chpr;
    int regCnt = gcursorS[sreg] - sreg * capS;
    int count = regCnt - ci * CHUNK;
    if (count <= 0) return;                          // uniform per block
    if (count > CHUNK) count = CHUNK;
    long m0 = (long)sreg * capS + (long)ci * CHUNK;
    int sbase = sreg << BSH;

    for (int b = t; b < MAXNB; b += 256) { hist[b] = 0; cnt2[b] = 0; }
    __syncthreads();

    uint4 r_[PERT];
    int bk_[PERT];
#pragma unroll
    for (int j = 0; j < PERT; ++j) {
        int le = t + j * 256;
        if (le < count) {
            uint4 rec = ldnt16(srcbin + m0 + le);
            int s = sbase | (rec.w & (BN - 1));
            unsigned dd = rec.w >> BSH;
            uint4 hv = h16[s];                        // 32KB window -> L1
            float2 e01 = up2(rec.x), e23 = up2(rec.y), e45 = up2(rec.z);
            float2 h01 = up2(hv.x),  h23 = up2(hv.y),  h45 = up2(hv.z);
            uint4 o;
            o.x = pk2(fmaxf(h01.x + e01.x, 0.f), fmaxf(h01.y + e01.y, 0.f));
            o.y = pk2(fmaxf(h23.x + e23.x, 0.f), fmaxf(h23.y + e23.y, 0.f));
            o.z = pk2(fmaxf(h45.x + e45.x, 0.f), fmaxf(h45.y + e45.y, 0.f));
            o.w = dd;                                 // full dst (20b)
            r_[j] = o;
            bk_[j] = dd >> BSH;
            atomicAdd(&hist[bk_[j]], 1);
        } else bk_[j] = -1;
    }
    __syncthreads();

    {   // scan hist[0..512) -> lofs
        int b0 = 2 * t, b1 = 2 * t + 1;
        int s0 = hist[b0], s1 = hist[b1];
        pairs[t] = s0 + s1;
        __syncthreads();
        for (int off = 1; off < 256; off <<= 1) {
            int a = (t >= off) ? pairs[t - off] : 0;
            __syncthreads();
            pairs[t] += a;
            __syncthreads();
        }
        int excl = (t == 0) ? 0 : pairs[t - 1];
        lofs[b0] = excl;
        lofs[b1] = excl + s0;
    }
    for (int b = t; b < NBd; b += 256) {
        int c = hist[b];
        base[b] = c ? atomicAdd(&gcursorD[b], c) : 0;
    }
    __syncthreads();

#pragma unroll
    for (int j = 0; j < PERT; ++j) {
        if (bk_[j] < 0) continue;
        int b = bk_[j];
        int r = atomicAdd(&cnt2[b], 1);
        pay[lofs[b] + r] = r_[j];
    }
    __syncthreads();

    for (int s2 = t; s2 < count; s2 += 256) {
        uint4 p = pay[s2];
        int b = p.w >> BSH;                           // bucket from full dst
        long gpos = (long)base[b] + (s2 - lofs[b]);
        p.w &= (BN - 1);                              // keep dloc only
        mbin[gpos] = p;
    }
}

// ===========================================================================
// layer B (owner-computes): per chunk build dloc-CSR in LDS; thread t owns
// dlocs {2t, 2t+1} and accumulates into registers. No accumulation atomics.
// ===========================================================================
#define LAYERB_CORE                                                           \
    __shared__ uint4 pay[CHUNK];            /* 48 KB */                       \
    __shared__ unsigned short slot[CHUNK];  /* 6 KB */                        \
    __shared__ int hist[BN];                /* 8 KB */                        \
    __shared__ int wsum[16];                                                  \
    int t = threadIdx.x;                                                      \
    int lane = t & 63, wid = t >> 6;                                          \
    int bk = blockIdx.x;                                                      \
    long kbeg = (long)bk * capD;                                              \
    int cnt = gcursorD[bk] - (int)kbeg;                                       \
    float a00 = 0.f, a01 = 0.f, a02 = 0.f, a03 = 0.f, a04 = 0.f, a05 = 0.f;   \
    float a10 = 0.f, a11 = 0.f, a12 = 0.f, a13 = 0.f, a14 = 0.f, a15 = 0.f;   \
    for (int c0 = 0; c0 < cnt; c0 += CHUNK) {                                 \
        int cc = cnt - c0; if (cc > CHUNK) cc = CHUNK;                        \
        hist[2 * t] = 0; hist[2 * t + 1] = 0;                                 \
        __syncthreads();                                                      \
        int dl_[PERTB];                                                       \
        _Pragma("unroll")                                                     \
        for (int j = 0; j < PERTB; ++j) {                                     \
            int le = t + j * LTB;                                             \
            if (le < cc) {                                                    \
                uint4 p = ldnt16(mbin + kbeg + c0 + le);                      \
                pay[le] = p;                                                  \
                dl_[j] = p.w & (BN - 1);                                      \
                atomicAdd(&hist[dl_[j]], 1);                                  \
            } else dl_[j] = -1;                                               \
        }                                                                     \
        __syncthreads();                                                      \
        int s0 = hist[2 * t], s1 = hist[2 * t + 1];                           \
        int v = s0 + s1;                                                      \
        int w = v;                                                            \
        _Pragma("unroll")                                                     \
        for (int o2 = 1; o2 < 64; o2 <<= 1) {                                 \
            int u = __shfl_up(w, o2, 64);                                     \
            if (lane >= o2) w += u;                                           \
        }                                                                     \
        if (lane == 63) wsum[wid] = w;                                        \
        __syncthreads();                                                      \
        if (wid == 0) {                                                       \
            int sv = (lane < 16) ? wsum[lane] : 0;                            \
            int ws = sv;                                                      \
            _Pragma("unroll")                                                 \
            for (int o2 = 1; o2 < 16; o2 <<= 1) {                             \
                int u = __shfl_up(ws, o2, 64);                                \
                if (lane >= o2) ws += u;                                      \
            }                                                                 \
            if (lane < 16) wsum[lane] = ws - sv;                              \
        }                                                                     \
        __syncthreads();                                                      \
        int start0 = wsum[wid] + (w - v);                                     \
        int start1 = start0 + s0;                                             \
        hist[2 * t] = start0; hist[2 * t + 1] = start1;                       \
        __syncthreads();                                                      \
        _Pragma("unroll")                                                     \
        for (int j = 0; j < PERTB; ++j) {                                     \
            if (dl_[j] < 0) continue;                                         \
            int sl = atomicAdd(&hist[dl_[j]], 1);                             \
            slot[sl] = (unsigned short)(t + j * LTB);                         \
        }                                                                     \
        __syncthreads();                                                      \
        for (int k = 0; k < s0; ++k) {                                        \
            uint4 p = pay[slot[start0 + k]];                                  \
            float2 m01 = up2(p.x), m23 = up2(p.y), m45 = up2(p.z);            \
            a00 += m01.x; a01 += m01.y; a02 += m23.x;                         \
            a03 += m23.y; a04 += m45.x; a05 += m45.y;                         \
        }                                                                     \
        for (int k = 0; k < s1; ++k) {                                        \
            uint4 p = pay[slot[start1 + k]];                                  \
            float2 m01 = up2(p.x), m23 = up2(p.y), m45 = up2(p.z);            \
            a10 += m01.x; a11 += m01.y; a12 += m23.x;                         \
            a13 += m23.y; a14 += m45.x; a15 += m45.y;                         \
        }                                                                     \
        __syncthreads();                                                      \
    }                                                                         \
    __shared__ float sW[HID * HID];                                           \
    __shared__ float sb[HID];                                                 \
    if (t < HID * HID) sW[t] = W[t];                                          \
    if (t < HID) sb[t] = b[t];                                                \
    __syncthreads();                                                          \
    int nodeBase = bk << BSH;

#define NODE_MM(TV, O)                                                        \
    float O[HID];                                                             \
    _Pragma("unroll")                                                         \
    for (int dd = 0; dd < HID; ++dd) O[dd] = sb[dd];                          \
    _Pragma("unroll")                                                         \
    for (int kk = 0; kk < HID; ++kk)                                          \
        _Pragma("unroll")                                                     \
        for (int dd = 0; dd < HID; ++dd) O[dd] += TV[kk] * sW[kk * HID + dd];

__global__ void __launch_bounds__(LTB) layerB_kernel(
        const uint4* __restrict__ h16,
        const uint4* __restrict__ mbin,
        const int* __restrict__ gcursorD,
        const float* __restrict__ W, const float* __restrict__ b,
        uint4* __restrict__ out16, int N, int capD) {
    LAYERB_CORE
    {
        int i = nodeBase + 2 * t;
        if (i < N) {
            uint4 hv = h16[i];
            float2 h01 = up2(hv.x), h23 = up2(hv.y), h45 = up2(hv.z);
            float tv[HID] = {h01.x + a00, h01.y + a01, h23.x + a02,
                             h23.y + a03, h45.x + a04, h45.y + a05};
            NODE_MM(tv, o)
#pragma unroll
            for (int dd = 0; dd < HID; ++dd) o[dd] = fmaxf(o[dd], 0.f);
            uint4 ov;
            ov.x = pk2(o[0], o[1]); ov.y = pk2(o[2], o[3]); ov.z = pk2(o[4], o[5]); ov.w = 0;
            out16[i] = ov;
        }
        i = nodeBase + 2 * t + 1;
        if (i < N) {
            uint4 hv = h16[i];
            float2 h01 = up2(hv.x), h23 = up2(hv.y), h45 = up2(hv.z);
            float tv[HID] = {h01.x + a10, h01.y + a11, h23.x + a12,
                             h23.y + a13, h45.x + a14, h45.y + a15};
            NODE_MM(tv, o)
#pragma unroll
            for (int dd = 0; dd < HID; ++dd) o[dd] = fmaxf(o[dd], 0.f);
            uint4 ov;
            ov.x = pk2(o[0], o[1]); ov.y = pk2(o[2], o[3]); ov.z = pk2(o[4], o[5]); ov.w = 0;
            out16[i] = ov;
        }
    }
}

__global__ void __launch_bounds__(LTB) layerB3_pool_kernel(
        const uint4* __restrict__ h16,
        const uint4* __restrict__ mbin,
        const int* __restrict__ gcursorD,
        const float* __restrict__ W, const float* __restrict__ b,
        const int* __restrict__ batch,
        float* __restrict__ sums, float* __restrict__ cnts,
        int N, int capD) {
    LAYERB_CORE
#pragma unroll
    for (int jj = 0; jj < 2; ++jj) {
        int i = nodeBase + 2 * t + jj;
        bool active = (i < N);
        float o[HID];
        int g = -1;
        if (active) {
            uint4 hv = h16[i];
            float2 h01 = up2(hv.x), h23 = up2(hv.y), h45 = up2(hv.z);
            float tv[HID];
            if (jj == 0) {
                tv[0] = h01.x + a00; tv[1] = h01.y + a01; tv[2] = h23.x + a02;
                tv[3] = h23.y + a03; tv[4] = h45.x + a04; tv[5] = h45.y + a05;
            } else {
                tv[0] = h01.x + a10; tv[1] = h01.y + a11; tv[2] = h23.x + a12;
                tv[3] = h23.y + a13; tv[4] = h45.x + a14; tv[5] = h45.y + a15;
            }
#pragma unroll
            for (int dd = 0; dd < HID; ++dd) o[dd] = sb[dd];
#pragma unroll
            for (int kk = 0; kk < HID; ++kk)
#pragma unroll
                for (int dd = 0; dd < HID; ++dd) o[dd] += tv[kk] * sW[kk * HID + dd];
            g = batch[i];
        } else {
#pragma unroll
            for (int dd = 0; dd < HID; ++dd) o[dd] = 0.f;
        }
        int g0 = __shfl(g, 0);
        bool uniform = __all(active) && __all(g == g0);
        if (uniform) {
#pragma unroll
            for (int dd = 0; dd < HID; ++dd) {
                float s = o[dd];
                for (int off2 = 32; off2 > 0; off2 >>= 1) s += __shfl_down(s, off2);
                if (lane == 0) atomicAdd(&sums[(size_t)g0 * HID + dd], s);
            }
            if (lane == 0) atomicAdd(&cnts[g0], 64.0f);
        } else if (active) {
#pragma unroll
            for (int dd = 0; dd < HID; ++dd) atomicAdd(&sums[(size_t)g * HID + dd], o[dd]);
            atomicAdd(&cnts[g], 1.0f);
        }
    }
}

// ===========================================================================
// tier D fallback (fp16 h)
// ===========================================================================
__global__ void edge_kernel(const uint4* __restrict__ h16, const float* __restrict__ edge_attr,
                            const int* __restrict__ src, const int* __restrict__ dst,
                            float* __restrict__ agg, int E) {
    long e = (long)blockIdx.x * blockDim.x + threadIdx.x;
    if (e >= E) return;
    int s = src[e], d = dst[e];
    const float2* ea = (const float2*)(edge_attr + (size_t)e * HID);
    uint4 hv = h16[s];
    float2 h01 = up2(hv.x), h23 = up2(hv.y), h45 = up2(hv.z);
    float2 a0 = ea[0], a1 = ea[1], a2 = ea[2];
    float* ag = agg + (size_t)d * HID;
    atomicAdd(ag + 0, fmaxf(h01.x + a0.x, 0.f));
    atomicAdd(ag + 1, fmaxf(h01.y + a0.y, 0.f));
    atomicAdd(ag + 2, fmaxf(h23.x + a1.x, 0.f));
    atomicAdd(ag + 3, fmaxf(h23.y + a1.y, 0.f));
    atomicAdd(ag + 4, fmaxf(h45.x + a2.x, 0.f));
    atomicAdd(ag + 5, fmaxf(h45.y + a2.y, 0.f));
}

__global__ void node_kernel(const uint4* __restrict__ h16, const float* __restrict__ agg,
                            const float* __restrict__ W, const float* __restrict__ b,
                            uint4* __restrict__ out16, int N, int do_relu) {
    __shared__ float sW[HID * HID];
    __shared__ float sb[HID];
    if (threadIdx.x < HID * HID) sW[threadIdx.x] = W[threadIdx.x];
    if (threadIdx.x < HID) sb[threadIdx.x] = b[threadIdx.x];
    __syncthreads();
    int i = blockIdx.x * blockDim.x + threadIdx.x;
    if (i >= N) return;
    uint4 hv = h16[i];
    float2 h01 = up2(hv.x), h23 = up2(hv.y), h45 = up2(hv.z);
    const float2* ap = (const float2*)(agg + (size_t)i * HID);
    float2 g0 = ap[0], g1 = ap[1], g2 = ap[2];
    float tv[HID];
    tv[0] = h01.x + g0.x; tv[1] = h01.y + g0.y;
    tv[2] = h23.x + g1.x; tv[3] = h23.y + g1.y;
    tv[4] = h45.x + g2.x; tv[5] = h45.y + g2.y;
    float o[HID];
#pragma unroll
    for (int d = 0; d < HID; ++d) o[d] = sb[d];
#pragma unroll
    for (int k = 0; k < HID; ++k)
#pragma unroll
        for (int d = 0; d < HID; ++d) o[d] += tv[k] * sW[k * HID + d];
    if (do_relu)
#pragma unroll
        for (int d = 0; d < HID; ++d) o[d] = fmaxf(o[d], 0.f);
    uint4 ov;
    ov.x = pk2(o[0], o[1]); ov.y = pk2(o[2], o[3]); ov.z = pk2(o[4], o[5]); ov.w = 0;
    out16[i] = ov;
}

__global__ void pool_kernel(const uint4* __restrict__ h16, const int* __restrict__ batch,
                            float* __restrict__ sums, float* __restrict__ cnts, int N) {
    int i = blockIdx.x * blockDim.x + threadIdx.x;
    int lane = threadIdx.x & 63;
    bool active = (i < N);
    float v[HID];
    int g = -1;
    if (active) {
        g = batch[i];
        uint4 hv = h16[i];
        float2 h01 = up2(hv.x), h23 = up2(hv.y), h45 = up2(hv.z);
        v[0] = h01.x; v[1] = h01.y; v[2] = h23.x; v[3] = h23.y; v[4] = h45.x; v[5] = h45.y;
    } else {
#pragma unroll
        for (int d = 0; d < HID; ++d) v[d] = 0.0f;
    }
    int g0 = __shfl(g, 0);
    bool uniform = __all(active) && __all(g == g0);
    if (uniform) {
#pragma unroll
        for (int d = 0; d < HID; ++d) {
            float s = v[d];
            for (int off = 32; off > 0; off >>= 1) s += __shfl_down(s, off);
            if (lane == 0) atomicAdd(&sums[(size_t)g0 * HID + d], s);
        }
        if (lane == 0) atomicAdd(&cnts[g0], 64.0f);
    } else if (active) {
#pragma unroll
        for (int d = 0; d < HID; ++d) atomicAdd(&sums[(size_t)g * HID + d], v[d]);
        atomicAdd(&cnts[g], 1.0f);
    }
}

__global__ void out_kernel(const float* __restrict__ sums, const float* __restrict__ cnts,
                           const float* __restrict__ Wl, const float* __restrict__ bl,
                           float* __restrict__ out) {
    int gI = blockIdx.x * blockDim.x + threadIdx.x;
    if (gI >= NUM_GRAPHS) return;
    float c = fmaxf(cnts[gI], 1.0f);
    float acc = bl[0];
#pragma unroll
    for (int d = 0; d < HID; ++d) acc += (sums[(size_t)gI * HID + d] / c) * Wl[d];
    out[gI] = acc;
}

// ===========================================================================
extern "C" void kernel_launch(void* const* d_in, const int* in_sizes, int n_in,
                              void* d_out, int out_size, void* d_ws, size_t ws_size,
                              hipStream_t stream) {
    const float* x         = (const float*)d_in[0];
    const int*   eidx      = (const int*)d_in[1];
    const float* edge_attr = (const float*)d_in[2];
    const int*   batch     = (const int*)d_in[3];
    const float* W1 = (const float*)d_in[4];
    const float* b1 = (const float*)d_in[5];
    const float* W2 = (const float*)d_in[6];
    const float* b2 = (const float*)d_in[7];
    const float* W3 = (const float*)d_in[8];
    const float* b3 = (const float*)d_in[9];
    const float* Wl = (const float*)d_in[10];
    const float* bl = (const float*)d_in[11];

    const int N = in_sizes[0] / HID;
    const int E = in_sizes[1] / 2;
    const int* src = eidx;
    const int* dst = eidx + E;

    const int TB = 256;
    const int nbl = (N + TB - 1) / TB;
    const int ebl = (E + TB - 1) / TB;
    const int pbl = (E + CHUNK - 1) / CHUNK;

    const int NB = (N + BN - 1) >> BSH;               // 489 buckets (both sides)
    const int chpr = (E / (NB > 0 ? NB : 1) + CHUNK + CHUNK - 1) / CHUNK;
    const int capS = chpr * CHUNK;
    const int capD = ((E / (NB > 0 ? NB : 1)) + 3072 + 1023) & ~1023;
    const long slotsS = (long)NB * capS + 64;
    const long slotsD = (long)NB * capD + 64;

    char* w = (char*)d_ws;
    size_t off = 0;
    auto alloc = [&](size_t bytes) { void* p = w + off; off += (bytes + 255) & ~(size_t)255; return p; };

    uint4* hX   = (uint4*)alloc((size_t)N * sizeof(uint4));   // 16MB
    uint4* hA   = (uint4*)alloc((size_t)N * sizeof(uint4));   // 16MB
    float* sums = (float*)alloc((size_t)NUM_GRAPHS * HID * sizeof(float));
    float* cnts = (float*)alloc((size_t)NUM_GRAPHS * sizeof(float));
    size_t tierDneed = off + (size_t)N * sizeof(uint4)        // hB
                     + (size_t)N * HID * sizeof(float);       // agg

    uint4* srcbin   = (uint4*)alloc((size_t)slotsS * sizeof(uint4));  // ~216MB
    uint4* mbin     = (uint4*)alloc((size_t)slotsD * sizeof(uint4));  // ~224MB
    int*   gcursorS = (int*)alloc((size_t)NB * sizeof(int));
    int*   gcursorD = (int*)alloc((size_t)NB * sizeof(int));
    size_t tierAneed = off;

    pad_kernel<<<nbl, TB, 0, stream>>>(x, hX, N);
    hipMemsetAsync(sums, 0, (size_t)NUM_GRAPHS * HID * sizeof(float), stream);
    hipMemsetAsync(cnts, 0, (size_t)NUM_GRAPHS * sizeof(float), stream);

    const int icb = (NB + TB - 1) / TB;

    if (NB <= MAXNB && N <= (1 << 20) && ws_size >= tierAneed) {
        // ---- one-time: bin edges by src bucket ----
        init_cursor_kernel<<<icb, TB, 0, stream>>>(gcursorS, NB, capS);
        prep_kernel<<<pbl, TB, 0, stream>>>(src, dst, edge_attr, gcursorS, srcbin, E, capS, NB);

        // ---- layer 1: hX -> hA ----
        init_cursor_kernel<<<icb, TB, 0, stream>>>(gcursorD, NB, capD);
        layerA_kernel<<<NB * chpr, TB, 0, stream>>>(hX, srcbin, gcursorS, gcursorD, mbin,
                                                    capS, chpr, NB);
        layerB_kernel<<<NB, LTB, 0, stream>>>(hX, mbin, gcursorD, W1, b1, hA, N, capD);

        // ---- layer 2: hA -> hX (reuse) ----
        init_cursor_kernel<<<icb, TB, 0, stream>>>(gcursorD, NB, capD);
        layerA_kernel<<<NB * chpr, TB, 0, stream>>>(hA, srcbin, gcursorS, gcursorD, mbin,
                                                    capS, chpr, NB);
        layerB_kernel<<<NB, LTB, 0, stream>>>(hA, mbin, gcursorD, W2, b2, hX, N, capD);

        // ---- layer 3 + pool: hX -> sums/cnts ----
        init_cursor_kernel<<<icb, TB, 0, stream>>>(gcursorD, NB, capD);
        layerA_kernel<<<NB * chpr, TB, 0, stream>>>(hX, srcbin, gcursorS, gcursorD, mbin,
                                                    capS, chpr, NB);
        layerB3_pool_kernel<<<NB, LTB, 0, stream>>>(hX, mbin, gcursorD, W3, b3,
                                                    batch, sums, cnts, N, capD);
    } else {
        // ---- tier D: atomic fallback ----
        uint4* hB  = (uint4*)((char*)w + tierDneed - (size_t)N * HID * sizeof(float)
                              - (size_t)N * sizeof(uint4));
        float* agg = (float*)((char*)w + tierDneed - (size_t)N * HID * sizeof(float));
        const size_t szAgg = (size_t)N * HID * sizeof(float);
        hipMemsetAsync(agg, 0, szAgg, stream);
        edge_kernel<<<ebl, TB, 0, stream>>>(hX, edge_attr, src, dst, agg, E);
        node_kernel<<<nbl, TB, 0, stream>>>(hX, agg, W1, b1, hA, N, 1);
        hipMemsetAsync(agg, 0, szAgg, stream);
        edge_kernel<<<ebl, TB, 0, stream>>>(hA, edge_attr, src, dst, agg, E);
        node_kernel<<<nbl, TB, 0, stream>>>(hA, agg, W2, b2, hB, N, 1);
        hipMemsetAsync(agg, 0, szAgg, stream);
        edge_kernel<<<ebl, TB, 0, stream>>>(hB, edge_attr, src, dst, agg, E);
        node_kernel<<<nbl, TB, 0, stream>>>(hB, agg, W3, b3, hA, N, 0);
        pool_kernel<<<nbl, TB, 0, stream>>>(hA, batch, sums, cnts, N);
    }

    out_kernel<<<(NUM_GRAPHS + TB - 1) / TB, TB, 0, stream>>>(sums, cnts, Wl, bl, (float*)d_out);
}